// Round 5
// baseline (642.482 us; speedup 1.0000x reference)
//
#include <hip/hip_runtime.h>
#include <hip/hip_fp16.h>
#include <math.h>
#include <stdint.h>

#define N_STEPS 256
#define DENSITY_SCALE 10.0f
#define REF_EPS 1e-8f
#define TILE_CAP 65536   // entries per tile (bulletproof: <= n_rays)

typedef uint32_t u32_a2 __attribute__((aligned(2)));
typedef uint2 uint2_a4 __attribute__((aligned(4)));

__device__ __forceinline__ float clip01(float v) {
    return fminf(fmaxf(v, 0.0f), 1.0f);
}

__device__ __forceinline__ float safe_inv(float d) {
    float denom = d;
    if (fabsf(d) < REF_EPS) {
        float s = (d > 0.0f) ? 1.0f : ((d < 0.0f) ? -1.0f : 0.0f);
        denom = s * REF_EPS + REF_EPS;   // may be 0 -> inf, matches jnp
    }
    return 1.0f / denom;
}

__device__ __forceinline__ uint32_t q255(float v) {
    return (uint32_t)__float2int_rn(clip01(v) * 255.0f);
}

// Conservative world-space tile bounds (eps = 0.25 cells); edge tiles open.
__device__ __forceinline__ float tile_lo(int k) {
    return (k == 0) ? -1e30f : ((64.0f * k - 0.25f) * (1.0f / 127.5f) - 1.0f);
}
__device__ __forceinline__ float tile_hi(int k) {
    return (k == 3) ?  1e30f : ((64.0f * k + 64.25f) * (1.0f / 127.5f) - 1.0f);
}
__device__ __forceinline__ void axis_clip(float o, float d, float lo, float hi,
                                          float& ta, float& tb) {
    if (fabsf(d) > 1e-6f) {
        float inv = 1.0f / d;
        float t0 = (lo - o) * inv, t1 = (hi - o) * inv;
        ta = fmaxf(ta, fminf(t0, t1));
        tb = fminf(tb, fmaxf(t0, t1));
    } else if (o < lo || o > hi) {
        ta = 1e30f; tb = -1e30f;
    }
}

// ---- repack: quad[z][y][x] = u8x4 {v(z,y,x), v(z,y+1,x), v(z+1,y,x), v(z+1,y+1,x)} ----
// Also zeroes compaction counter + per-tile counters.
__global__ __launch_bounds__(256) void repack_quad_kernel(
    const float* __restrict__ g, uint32_t* __restrict__ quad,
    int* __restrict__ counter, int* __restrict__ tileCnt)
{
    if (blockIdx.x == 0) {
        if (threadIdx.x == 0) *counter = 0;
        if (threadIdx.x < 64) tileCnt[threadIdx.x] = 0;
    }
    int t = blockIdx.x * blockDim.x + threadIdx.x;     // [0, 256*256*64)
    int x4 = (t & 63) << 2;
    int zy = t >> 6;
    int z = zy >> 8;
    int y = zy & 255;
    int yp = (y == 255) ? y : y + 1;                   // clamped rows: unused by march
    int zp = (z == 255) ? z : z + 1;
    float4 a = *(const float4*)(g + ((z  << 16) + (y  << 8) + x4));
    float4 b = *(const float4*)(g + ((z  << 16) + (yp << 8) + x4));
    float4 c = *(const float4*)(g + ((zp << 16) + (y  << 8) + x4));
    float4 d = *(const float4*)(g + ((zp << 16) + (yp << 8) + x4));
    uint4 o;
    o.x = q255(a.x) | (q255(b.x) << 8) | (q255(c.x) << 16) | (q255(d.x) << 24);
    o.y = q255(a.y) | (q255(b.y) << 8) | (q255(c.y) << 16) | (q255(d.y) << 24);
    o.z = q255(a.z) | (q255(b.z) << 8) | (q255(c.z) << 16) | (q255(d.z) << 24);
    o.w = q255(a.w) | (q255(b.w) << 8) | (q255(c.w) << 16) | (q255(d.w) << 24);
    *(uint4*)(quad + ((zy << 8) + x4)) = o;
}

// ---- setup: slab test, compaction, per-ray accumulator init, tile binning ----
__global__ __launch_bounds__(256) void setup_tiles_kernel(
    const float* __restrict__ rays, float* __restrict__ out,
    float* __restrict__ compactF, int* __restrict__ compactI,
    int* __restrict__ counter, int* __restrict__ tileCnt,
    uint32_t* __restrict__ tileList, float* __restrict__ acc, int n_rays)
{
    int ray = blockIdx.x * blockDim.x + threadIdx.x;
    bool valid = false;
    float ox = 0, oy = 0, oz = 0, dx = 0, dy = 0, dz = 0, tmin = 0, seg = 0;

    if (ray < n_rays) {
        const float* r = rays + ray * 6;
        ox = r[0]; oy = r[1]; oz = r[2];
        dx = r[3]; dy = r[4]; dz = r[5];
        float nrm = sqrtf(dx*dx + dy*dy + dz*dz) + REF_EPS;
        float inv_n = 1.0f / nrm;
        dx *= inv_n; dy *= inv_n; dz *= inv_n;
        float ixv = safe_inv(dx), iyv = safe_inv(dy), izv = safe_inv(dz);
        float tax = (-1.0f - ox) * ixv, tbx = (1.0f - ox) * ixv;
        float tay = (-1.0f - oy) * iyv, tby = (1.0f - oy) * iyv;
        float taz = (-1.0f - oz) * izv, tbz = (1.0f - oz) * izv;
        tmin = fmaxf(fmaxf(fminf(tax, tbx), fminf(tay, tby)), fminf(taz, tbz));
        float tmax = fminf(fminf(fmaxf(tax, tbx), fmaxf(tay, tby)), fmaxf(taz, tbz));
        tmin = fmaxf(tmin, 0.0f);
        valid = tmax > tmin;
        seg = valid ? (tmax - tmin) : 0.0f;
    }

    unsigned long long mask = __ballot(valid);
    int lane = threadIdx.x & 63;
    int nbefore = __popcll(mask & ((1ull << lane) - 1ull));
    int total = __popcll(mask);
    int base = 0;
    if (lane == 0 && total) base = atomicAdd(counter, total);
    base = __shfl(base, 0);
    int cidx = base + nbefore;

    if (valid) {
        float4* dst = (float4*)(compactF + (size_t)cidx * 8);
        dst[0] = make_float4(ox, oy, oz, dx);
        dst[1] = make_float4(dy, dz, tmin, seg);
        compactI[cidx] = ray;
        acc[cidx] = 0.0f;
    } else if (ray < n_rays) {
        out[ray] = 1.0f;
    }

    // tile binning: wave-uniform loop, per-tile wave-aggregated atomics
    for (int t = 0; t < 64; ++t) {
        bool hit = false;
        if (valid) {
            int ttx = t & 3, tty = (t >> 2) & 3, ttz = t >> 4;
            float ta = tmin, tb = tmin + seg;
            axis_clip(ox, dx, tile_lo(ttx), tile_hi(ttx), ta, tb);
            axis_clip(oy, dy, tile_lo(tty), tile_hi(tty), ta, tb);
            axis_clip(oz, dz, tile_lo(ttz), tile_hi(ttz), ta, tb);
            hit = (tb >= ta);
        }
        unsigned long long m = __ballot(hit);
        if (m == 0ull) continue;
        int tot = __popcll(m);
        int rank = __popcll(m & ((1ull << lane) - 1ull));
        int tbase = 0;
        if (lane == 0) tbase = atomicAdd(&tileCnt[t], tot);
        tbase = __shfl(tbase, 0);
        if (hit) tileList[(size_t)t * TILE_CAP + tbase + rank] = (uint32_t)cidx;
    }
}

// ---- march: tile-partitioned; blockIdx&63 = tile -> XCD pinning via %8 ----
__global__ __launch_bounds__(256) void march_tiles_kernel(
    const float* __restrict__ compactF, const int* __restrict__ tileCnt,
    const uint32_t* __restrict__ tileList, const uint32_t* __restrict__ quad,
    float* __restrict__ acc)
{
    int tile  = blockIdx.x & 63;
    int chunk = blockIdx.x >> 6;                 // 0..127
    int tx = tile & 3, ty = (tile >> 2) & 3, tz = tile >> 4;
    int group = threadIdx.x >> 3;                // 0..31
    int sub   = threadIdx.x & 7;
    int cnt = tileCnt[tile];
    if (cnt > TILE_CAP) cnt = TILE_CAP;

    float wlx = tile_lo(tx), whx = tile_hi(tx);
    float wly = tile_lo(ty), why = tile_hi(ty);
    float wlz = tile_lo(tz), whz = tile_hi(tz);

    for (int e = chunk * 32 + group; e < cnt; e += 4096) {
        int ridx = tileList[(size_t)tile * TILE_CAP + e];
        const float4* c = (const float4*)(compactF + (size_t)ridx * 8);
        float4 c0 = c[0], c1 = c[1];
        float ox = c0.x, oy = c0.y, oz = c0.z;
        float dx = c0.w, dy = c1.x, dz = c1.y;
        float tmin = c1.z, seg = c1.w;
        float step = seg * (1.0f / (float)N_STEPS);

        float ta = tmin, tb = tmin + seg;
        axis_clip(ox, dx, wlx, whx, ta, tb);
        axis_clip(oy, dy, wly, why, ta, tb);
        axis_clip(oz, dz, wlz, whz, ta, tb);
        if (tb < ta) continue;

        int i_lo = (int)ceilf((ta - tmin) / step - 0.5f - 1e-3f);
        int i_hi = (int)floorf((tb - tmin) / step - 0.5f + 1e-3f);
        i_lo = max(i_lo, 0);
        i_hi = min(i_hi, N_STEPS - 1);

        float sum = 0.0f;
        for (int i = i_lo + sub; i <= i_hi; i += 8) {
            float frac = ((float)i + 0.5f) * (1.0f / (float)N_STEPS);
            float t = fmaf(seg, frac, tmin);
            float px = fmaf(t, dx, ox);
            float py = fmaf(t, dy, oy);
            float pz = fmaf(t, dz, oz);
            float gx = (px + 1.0f) * (0.5f * 255.0f);
            float gy = (py + 1.0f) * (0.5f * 255.0f);
            float gz = (pz + 1.0f) * (0.5f * 255.0f);
            int x0 = (int)fminf(fmaxf(floorf(gx), 0.0f), 254.0f);
            int y0 = (int)fminf(fmaxf(floorf(gy), 0.0f), 254.0f);
            int z0 = (int)fminf(fmaxf(floorf(gz), 0.0f), 254.0f);
            // exact ownership: each sample processed by exactly one tile
            if (((x0 >> 6) != tx) | ((y0 >> 6) != ty) | ((z0 >> 6) != tz)) continue;
            float fx = fminf(fmaxf(gx - (float)x0, 0.0f), 1.0f);
            float fy = fminf(fmaxf(gy - (float)y0, 0.0f), 1.0f);
            float fz = fminf(fmaxf(gz - (float)z0, 0.0f), 1.0f);

            int vidx = (z0 << 16) + (y0 << 8) + x0;
            uint2 v = *(const uint2_a4*)(quad + vidx);
            float c000 = (float)( v.x        & 0xffu);
            float c010 = (float)((v.x >>  8) & 0xffu);
            float c100 = (float)((v.x >> 16) & 0xffu);
            float c110 = (float)( v.x >> 24        );
            float c001 = (float)( v.y        & 0xffu);
            float c011 = (float)((v.y >>  8) & 0xffu);
            float c101 = (float)((v.y >> 16) & 0xffu);
            float c111 = (float)( v.y >> 24        );

            float omfx = 1.0f - fx;
            float c00 = c000 * omfx + c001 * fx;
            float c01 = c010 * omfx + c011 * fx;
            float c10 = c100 * omfx + c101 * fx;
            float c11 = c110 * omfx + c111 * fx;
            float omfy = 1.0f - fy;
            float cc0 = c00 * omfy + c01 * fy;
            float cc1 = c10 * omfy + c11 * fy;
            sum += cc0 * (1.0f - fz) + cc1 * fz;   // scaled by 255
        }

        sum += __shfl_xor(sum, 1);
        sum += __shfl_xor(sum, 2);
        sum += __shfl_xor(sum, 4);
        if (sub == 0 && sum != 0.0f) atomicAdd(&acc[ridx], sum);
    }
}

__global__ __launch_bounds__(256) void finalize_kernel(
    const float* __restrict__ compactF, const int* __restrict__ compactI,
    const int* __restrict__ counter, const float* __restrict__ acc,
    float* __restrict__ out)
{
    int r = blockIdx.x * blockDim.x + threadIdx.x;
    if (r >= *counter) return;
    float seg = compactF[(size_t)r * 8 + 7];
    float dt = seg * (1.0f / (float)N_STEPS);
    float tau = (DENSITY_SCALE / 255.0f) * acc[r] * dt;
    out[compactI[r]] = expf(-tau);
}

// ================= fallback: round-4 path (monolithic march) =================
__global__ __launch_bounds__(256) void setup_kernel(
    const float* __restrict__ rays, float* __restrict__ out,
    float* __restrict__ compactF, int* __restrict__ compactI,
    int* __restrict__ counter, int n_rays)
{
    int ray = blockIdx.x * blockDim.x + threadIdx.x;
    bool valid = false;
    float ox = 0, oy = 0, oz = 0, dx = 0, dy = 0, dz = 0, tmin = 0, seg = 0;
    if (ray < n_rays) {
        const float* r = rays + ray * 6;
        ox = r[0]; oy = r[1]; oz = r[2];
        dx = r[3]; dy = r[4]; dz = r[5];
        float nrm = sqrtf(dx*dx + dy*dy + dz*dz) + REF_EPS;
        float inv_n = 1.0f / nrm;
        dx *= inv_n; dy *= inv_n; dz *= inv_n;
        float ixv = safe_inv(dx), iyv = safe_inv(dy), izv = safe_inv(dz);
        float tax = (-1.0f - ox) * ixv, tbx = (1.0f - ox) * ixv;
        float tay = (-1.0f - oy) * iyv, tby = (1.0f - oy) * iyv;
        float taz = (-1.0f - oz) * izv, tbz = (1.0f - oz) * izv;
        tmin = fmaxf(fmaxf(fminf(tax, tbx), fminf(tay, tby)), fminf(taz, tbz));
        float tmax = fminf(fminf(fmaxf(tax, tbx), fmaxf(tay, tby)), fmaxf(taz, tbz));
        tmin = fmaxf(tmin, 0.0f);
        valid = tmax > tmin;
        seg = valid ? (tmax - tmin) : 0.0f;
    }
    unsigned long long mask = __ballot(valid);
    int lane = threadIdx.x & 63;
    int nbefore = __popcll(mask & ((1ull << lane) - 1ull));
    int total = __popcll(mask);
    int base = 0;
    if (lane == 0 && total) base = atomicAdd(counter, total);
    base = __shfl(base, 0);
    if (valid) {
        int idx = base + nbefore;
        float4* dst = (float4*)(compactF + (size_t)idx * 8);
        dst[0] = make_float4(ox, oy, oz, dx);
        dst[1] = make_float4(dy, dz, tmin, seg);
        compactI[idx] = ray;
    } else if (ray < n_rays) {
        out[ray] = 1.0f;
    }
}

__global__ __launch_bounds__(256) void march_kernel(
    const float* __restrict__ compactF, const int* __restrict__ compactI,
    const int* __restrict__ counter, const uint32_t* __restrict__ quad,
    float* __restrict__ out)
{
    int gid = blockIdx.x * blockDim.x + threadIdx.x;
    int sub = gid & 7;
    int nvalid = *counter;
    int stride = (gridDim.x * blockDim.x) >> 3;
    for (int ray = gid >> 3; ray < nvalid; ray += stride) {
        const float4* c = (const float4*)(compactF + (size_t)ray * 8);
        float4 c0 = c[0], c1 = c[1];
        float ox = c0.x, oy = c0.y, oz = c0.z;
        float dx = c0.w, dy = c1.x, dz = c1.y;
        float tmin = c1.z, seg = c1.w;
        float sum = 0.0f;
        #pragma unroll 4
        for (int i = sub; i < N_STEPS; i += 8) {
            float frac = ((float)i + 0.5f) * (1.0f / (float)N_STEPS);
            float t = fmaf(seg, frac, tmin);
            float px = fmaf(t, dx, ox);
            float py = fmaf(t, dy, oy);
            float pz = fmaf(t, dz, oz);
            float gx = (px + 1.0f) * (0.5f * 255.0f);
            float gy = (py + 1.0f) * (0.5f * 255.0f);
            float gz = (pz + 1.0f) * (0.5f * 255.0f);
            int x0 = (int)fminf(fmaxf(floorf(gx), 0.0f), 254.0f);
            int y0 = (int)fminf(fmaxf(floorf(gy), 0.0f), 254.0f);
            int z0 = (int)fminf(fmaxf(floorf(gz), 0.0f), 254.0f);
            float fx = fminf(fmaxf(gx - (float)x0, 0.0f), 1.0f);
            float fy = fminf(fmaxf(gy - (float)y0, 0.0f), 1.0f);
            float fz = fminf(fmaxf(gz - (float)z0, 0.0f), 1.0f);
            int vidx = (z0 << 16) + (y0 << 8) + x0;
            uint2 v = *(const uint2_a4*)(quad + vidx);
            float c000 = (float)( v.x        & 0xffu);
            float c010 = (float)((v.x >>  8) & 0xffu);
            float c100 = (float)((v.x >> 16) & 0xffu);
            float c110 = (float)( v.x >> 24        );
            float c001 = (float)( v.y        & 0xffu);
            float c011 = (float)((v.y >>  8) & 0xffu);
            float c101 = (float)((v.y >> 16) & 0xffu);
            float c111 = (float)( v.y >> 24        );
            float omfx = 1.0f - fx;
            float c00 = c000 * omfx + c001 * fx;
            float c01 = c010 * omfx + c011 * fx;
            float c10 = c100 * omfx + c101 * fx;
            float c11 = c110 * omfx + c111 * fx;
            float omfy = 1.0f - fy;
            float cc0 = c00 * omfy + c01 * fy;
            float cc1 = c10 * omfy + c11 * fy;
            sum += cc0 * (1.0f - fz) + cc1 * fz;
        }
        sum += __shfl_xor(sum, 1);
        sum += __shfl_xor(sum, 2);
        sum += __shfl_xor(sum, 4);
        if (sub == 0) {
            float dt = seg * (1.0f / (float)N_STEPS);
            float tau = (DENSITY_SCALE / 255.0f) * sum * dt;
            out[compactI[ray]] = expf(-tau);
        }
    }
}

// ================= fallback: round-1 fp32 direct path =================
__global__ __launch_bounds__(256) void transmittance_kernel(
    const float* __restrict__ rays, const float* __restrict__ grid,
    float* __restrict__ out, int n_rays)
{
    int gid = blockIdx.x * blockDim.x + threadIdx.x;
    int ray = gid >> 2;
    int sub = gid & 3;
    if (ray >= n_rays) return;
    const float* r = rays + ray * 6;
    float ox = r[0], oy = r[1], oz = r[2];
    float dx = r[3], dy = r[4], dz = r[5];
    float nrm = sqrtf(dx*dx + dy*dy + dz*dz) + REF_EPS;
    float inv_n = 1.0f / nrm;
    dx *= inv_n; dy *= inv_n; dz *= inv_n;
    float ixv = safe_inv(dx), iyv = safe_inv(dy), izv = safe_inv(dz);
    float tax = (-1.0f - ox) * ixv, tbx = (1.0f - ox) * ixv;
    float tay = (-1.0f - oy) * iyv, tby = (1.0f - oy) * iyv;
    float taz = (-1.0f - oz) * izv, tbz = (1.0f - oz) * izv;
    float tmin = fmaxf(fmaxf(fminf(tax, tbx), fminf(tay, tby)), fminf(taz, tbz));
    float tmax = fminf(fminf(fmaxf(tax, tbx), fmaxf(tay, tby)), fmaxf(taz, tbz));
    tmin = fmaxf(tmin, 0.0f);
    bool valid = tmax > tmin;
    float result = 1.0f;
    float seg = valid ? (tmax - tmin) : 0.0f;
    float sum = 0.0f;
    if (valid) {
        #pragma unroll 4
        for (int i = sub; i < N_STEPS; i += 4) {
            float frac = ((float)i + 0.5f) * (1.0f / (float)N_STEPS);
            float t = fmaf(seg, frac, tmin);
            float px = fmaf(t, dx, ox);
            float py = fmaf(t, dy, oy);
            float pz = fmaf(t, dz, oz);
            float gx = (px + 1.0f) * (0.5f * 255.0f);
            float gy = (py + 1.0f) * (0.5f * 255.0f);
            float gz = (pz + 1.0f) * (0.5f * 255.0f);
            int x0 = (int)fminf(fmaxf(floorf(gx), 0.0f), 254.0f);
            int y0 = (int)fminf(fmaxf(floorf(gy), 0.0f), 254.0f);
            int z0 = (int)fminf(fmaxf(floorf(gz), 0.0f), 254.0f);
            float fx = fminf(fmaxf(gx - (float)x0, 0.0f), 1.0f);
            float fy = fminf(fmaxf(gy - (float)y0, 0.0f), 1.0f);
            float fz = fminf(fmaxf(gz - (float)z0, 0.0f), 1.0f);
            const float* p0 = grid + ((z0 << 16) + (y0 << 8) + x0);
            const float* p1 = p0 + 65536;
            float c000 = p0[0],   c001 = p0[1];
            float c010 = p0[256], c011 = p0[257];
            float c100 = p1[0],   c101 = p1[1];
            float c110 = p1[256], c111 = p1[257];
            float omfx = 1.0f - fx;
            float c00 = c000 * omfx + c001 * fx;
            float c01 = c010 * omfx + c011 * fx;
            float c10 = c100 * omfx + c101 * fx;
            float c11 = c110 * omfx + c111 * fx;
            float omfy = 1.0f - fy;
            float cc0 = c00 * omfy + c01 * fy;
            float cc1 = c10 * omfy + c11 * fy;
            sum += cc0 * (1.0f - fz) + cc1 * fz;
        }
    }
    sum += __shfl_xor(sum, 1);
    sum += __shfl_xor(sum, 2);
    if (valid) {
        float dt = seg * (1.0f / (float)N_STEPS);
        float tau = DENSITY_SCALE * sum * dt;
        result = expf(-tau);
    }
    if (sub == 0) out[ray] = result;
}

extern "C" void kernel_launch(void* const* d_in, const int* in_sizes, int n_in,
                              void* d_out, int out_size, void* d_ws, size_t ws_size,
                              hipStream_t stream) {
    const float* rays = (const float*)d_in[0];   // [65536, 6] fp32
    const float* grid = (const float*)d_in[1];   // [256,256,256] fp32
    float* out = (float*)d_out;
    int n_rays = in_sizes[0] / 6;
    int n_grid = in_sizes[1];                    // 16777216

    const size_t QUAD_BYTES = (size_t)n_grid * 4;            // 64 MB
    const size_t CF_BYTES   = (size_t)n_rays * 8 * 4;        // 2 MB
    const size_t CI_BYTES   = (size_t)n_rays * 4;            // 256 KB
    const size_t TL_BYTES   = (size_t)64 * TILE_CAP * 4;     // 16 MB
    const size_t ACC_BYTES  = (size_t)n_rays * 4;            // 256 KB
    const size_t TC_BYTES   = 64 * 4 + 64;                   // tileCnt + counter
    const size_t need_tiled = QUAD_BYTES + CF_BYTES + CI_BYTES + TL_BYTES + ACC_BYTES + TC_BYTES;
    const size_t need_mono  = QUAD_BYTES + CF_BYTES + CI_BYTES + 256;

    char* p = (char*)d_ws;
    if (ws_size >= need_tiled) {
        uint32_t* quad     = (uint32_t*)p;                 p += QUAD_BYTES;
        float*    compactF = (float*)p;                    p += CF_BYTES;
        int*      compactI = (int*)p;                      p += CI_BYTES;
        uint32_t* tileList = (uint32_t*)p;                 p += TL_BYTES;
        float*    acc      = (float*)p;                    p += ACC_BYTES;
        int*      tileCnt  = (int*)p;                      p += 64 * 4;
        int*      counter  = (int*)p;

        int rp_threads = n_grid / 4;
        repack_quad_kernel<<<(rp_threads + 255) / 256, 256, 0, stream>>>(
            grid, quad, counter, tileCnt);
        setup_tiles_kernel<<<(n_rays + 255) / 256, 256, 0, stream>>>(
            rays, out, compactF, compactI, counter, tileCnt, tileList, acc, n_rays);
        // 64 tiles x 128 chunks: tile = blockIdx & 63 -> XCD = blockIdx % 8 pins
        // all of tile t's blocks to XCD t%8; oversubscription phases tiles.
        march_tiles_kernel<<<64 * 128, 256, 0, stream>>>(
            compactF, tileCnt, tileList, quad, acc);
        finalize_kernel<<<(n_rays + 255) / 256, 256, 0, stream>>>(
            compactF, compactI, counter, acc, out);
    } else if (ws_size >= need_mono) {
        uint32_t* quad     = (uint32_t*)p;                 p += QUAD_BYTES;
        float*    compactF = (float*)p;                    p += CF_BYTES;
        int*      compactI = (int*)p;                      p += CI_BYTES;
        int*      counter  = (int*)p;
        int rp_threads = n_grid / 4;
        repack_quad_kernel<<<(rp_threads + 255) / 256, 256, 0, stream>>>(
            grid, quad, counter, counter + 16);  // tileCnt scratch unused by mono path
        setup_kernel<<<(n_rays + 255) / 256, 256, 0, stream>>>(
            rays, out, compactF, compactI, counter, n_rays);
        march_kernel<<<1024, 256, 0, stream>>>(compactF, compactI, counter, quad, out);
    } else {
        int total_threads = n_rays * 4;
        transmittance_kernel<<<(total_threads + 255) / 256, 256, 0, stream>>>(
            rays, grid, out, n_rays);
    }
}

// Round 6
// 192.119 us; speedup vs baseline: 3.3442x; 3.3442x over previous
//
#include <hip/hip_runtime.h>
#include <hip/hip_fp16.h>
#include <math.h>
#include <stdint.h>

#define N_STEPS 256
#define DENSITY_SCALE 10.0f
#define REF_EPS 1e-8f
#define TILE_CAP 65536   // entries per tile (bulletproof: <= n_rays)

typedef uint2 uint2_a4 __attribute__((aligned(4)));

__device__ __forceinline__ float clip01(float v) {
    return fminf(fmaxf(v, 0.0f), 1.0f);
}

__device__ __forceinline__ float safe_inv(float d) {
    float denom = d;
    if (fabsf(d) < REF_EPS) {
        float s = (d > 0.0f) ? 1.0f : ((d < 0.0f) ? -1.0f : 0.0f);
        denom = s * REF_EPS + REF_EPS;   // may be 0 -> inf, matches jnp
    }
    return 1.0f / denom;
}

__device__ __forceinline__ uint32_t q255(float v) {
    return (uint32_t)__float2int_rn(clip01(v) * 255.0f);
}

// Conservative world-space tile bounds (eps = 0.25 cells); edge tiles open.
__device__ __forceinline__ float tile_lo(int k) {
    return (k == 0) ? -1e30f : ((64.0f * k - 0.25f) * (1.0f / 127.5f) - 1.0f);
}
__device__ __forceinline__ float tile_hi(int k) {
    return (k == 3) ?  1e30f : ((64.0f * k + 64.25f) * (1.0f / 127.5f) - 1.0f);
}
__device__ __forceinline__ void axis_clip(float o, float d, float lo, float hi,
                                          float& ta, float& tb) {
    if (fabsf(d) > 1e-6f) {
        float inv = 1.0f / d;
        float t0 = (lo - o) * inv, t1 = (hi - o) * inv;
        ta = fmaxf(ta, fminf(t0, t1));
        tb = fminf(tb, fmaxf(t0, t1));
    } else if (o < lo || o > hi) {
        ta = 1e30f; tb = -1e30f;
    }
}

// candidate tile range along one axis from segment's grid-coord extent
__device__ __forceinline__ void tile_range(float o, float d, float t0, float t1,
                                           int& kmin, int& kmax) {
    float g0 = (fmaf(t0, d, o) + 1.0f) * (0.5f * 255.0f);
    float g1 = (fmaf(t1, d, o) + 1.0f) * (0.5f * 255.0f);
    float gmin = fminf(g0, g1), gmax = fmaxf(g0, g1);
    kmin = (int)floorf((gmin - 0.25f) * (1.0f / 64.0f));
    kmax = (int)floorf((gmax + 0.25f) * (1.0f / 64.0f));
    kmin = max(0, min(3, kmin));
    kmax = max(0, min(3, kmax));
}

// ---- repack: quad[z][y][x] = u8x4 {v(z,y,x), v(z,y+1,x), v(z+1,y,x), v(z+1,y+1,x)} ----
__global__ __launch_bounds__(256) void repack_quad_kernel(
    const float* __restrict__ g, uint32_t* __restrict__ quad,
    int* __restrict__ counter, int* __restrict__ tileCnt)
{
    if (blockIdx.x == 0) {
        if (threadIdx.x == 0) *counter = 0;
        if (threadIdx.x < 64) tileCnt[threadIdx.x] = 0;
    }
    int t = blockIdx.x * blockDim.x + threadIdx.x;     // [0, 256*256*64)
    int x4 = (t & 63) << 2;
    int zy = t >> 6;
    int z = zy >> 8;
    int y = zy & 255;
    int yp = (y == 255) ? y : y + 1;                   // clamped rows: unused by march
    int zp = (z == 255) ? z : z + 1;
    float4 a = *(const float4*)(g + ((z  << 16) + (y  << 8) + x4));
    float4 b = *(const float4*)(g + ((z  << 16) + (yp << 8) + x4));
    float4 c = *(const float4*)(g + ((zp << 16) + (y  << 8) + x4));
    float4 d = *(const float4*)(g + ((zp << 16) + (yp << 8) + x4));
    uint4 o;
    o.x = q255(a.x) | (q255(b.x) << 8) | (q255(c.x) << 16) | (q255(d.x) << 24);
    o.y = q255(a.y) | (q255(b.y) << 8) | (q255(c.y) << 16) | (q255(d.y) << 24);
    o.z = q255(a.z) | (q255(b.z) << 8) | (q255(c.z) << 16) | (q255(d.z) << 24);
    o.w = q255(a.w) | (q255(b.w) << 8) | (q255(c.w) << 16) | (q255(d.w) << 24);
    *(uint4*)(quad + ((zy << 8) + x4)) = o;
}

// ---- setup v2: slab test + compaction + LDS-aggregated tile binning ----
__global__ __launch_bounds__(256) void setup_tiles_kernel(
    const float* __restrict__ rays, float* __restrict__ out,
    float* __restrict__ compactF, int* __restrict__ compactI,
    int* __restrict__ counter, int* __restrict__ tileCnt,
    uint32_t* __restrict__ tileList, float* __restrict__ acc, int n_rays)
{
    __shared__ int h[64];      // block histogram
    __shared__ int cur[64];    // block cursor
    __shared__ int basev[64];  // global base per tile for this block
    if (threadIdx.x < 64) { h[threadIdx.x] = 0; cur[threadIdx.x] = 0; }
    __syncthreads();

    int ray = blockIdx.x * blockDim.x + threadIdx.x;
    bool valid = false;
    float ox = 0, oy = 0, oz = 0, dx = 0, dy = 0, dz = 0, tmin = 0, seg = 0;

    if (ray < n_rays) {
        const float* r = rays + ray * 6;
        ox = r[0]; oy = r[1]; oz = r[2];
        dx = r[3]; dy = r[4]; dz = r[5];
        float nrm = sqrtf(dx*dx + dy*dy + dz*dz) + REF_EPS;
        float inv_n = 1.0f / nrm;
        dx *= inv_n; dy *= inv_n; dz *= inv_n;
        float ixv = safe_inv(dx), iyv = safe_inv(dy), izv = safe_inv(dz);
        float tax = (-1.0f - ox) * ixv, tbx = (1.0f - ox) * ixv;
        float tay = (-1.0f - oy) * iyv, tby = (1.0f - oy) * iyv;
        float taz = (-1.0f - oz) * izv, tbz = (1.0f - oz) * izv;
        tmin = fmaxf(fmaxf(fminf(tax, tbx), fminf(tay, tby)), fminf(taz, tbz));
        float tmax = fminf(fminf(fmaxf(tax, tbx), fmaxf(tay, tby)), fmaxf(taz, tbz));
        tmin = fmaxf(tmin, 0.0f);
        valid = tmax > tmin;
        seg = valid ? (tmax - tmin) : 0.0f;
    }

    // compaction (1 global atomic per wave on one counter — cheap)
    unsigned long long mask = __ballot(valid);
    int lane = threadIdx.x & 63;
    int nbefore = __popcll(mask & ((1ull << lane) - 1ull));
    int total = __popcll(mask);
    int base = 0;
    if (lane == 0 && total) base = atomicAdd(counter, total);
    base = __shfl(base, 0);
    int cidx = base + nbefore;

    if (valid) {
        float4* dst = (float4*)(compactF + (size_t)cidx * 8);
        dst[0] = make_float4(ox, oy, oz, dx);
        dst[1] = make_float4(dy, dz, tmin, seg);
        compactI[cidx] = ray;
        acc[cidx] = 0.0f;
    } else if (ray < n_rays) {
        out[ray] = 1.0f;
    }

    // per-thread tile hit mask: candidate box (identical hit set to full 64-way
    // slab test — box condition == x/y/z slab overlap), pruned by 3-axis clip
    unsigned long long hitmask = 0ull;
    if (valid) {
        float te = tmin + seg;
        int txl, txh, tyl, tyh, tzl, tzh;
        tile_range(ox, dx, tmin, te, txl, txh);
        tile_range(oy, dy, tmin, te, tyl, tyh);
        tile_range(oz, dz, tmin, te, tzl, tzh);
        for (int ttz = tzl; ttz <= tzh; ++ttz)
            for (int tty = tyl; tty <= tyh; ++tty)
                for (int ttx = txl; ttx <= txh; ++ttx) {
                    float ta = tmin, tb = te;
                    axis_clip(ox, dx, tile_lo(ttx), tile_hi(ttx), ta, tb);
                    axis_clip(oy, dy, tile_lo(tty), tile_hi(tty), ta, tb);
                    axis_clip(oz, dz, tile_lo(ttz), tile_hi(ttz), ta, tb);
                    if (tb >= ta)
                        hitmask |= 1ull << ((ttz << 4) + (tty << 2) + ttx);
                }
    }

    // LDS histogram
    unsigned long long m = hitmask;
    while (m) {
        int t = __ffsll((long long)m) - 1;
        m &= m - 1;
        atomicAdd(&h[t], 1);
    }
    __syncthreads();

    // one parallel global atomic per non-empty tile per block
    if (threadIdx.x < 64 && h[threadIdx.x] > 0)
        basev[threadIdx.x] = atomicAdd(&tileCnt[threadIdx.x], h[threadIdx.x]);
    __syncthreads();

    // slot assignment via LDS cursor
    m = hitmask;
    while (m) {
        int t = __ffsll((long long)m) - 1;
        m &= m - 1;
        int slot = basev[t] + atomicAdd(&cur[t], 1);
        if (slot < TILE_CAP)
            tileList[(size_t)t * TILE_CAP + slot] = (uint32_t)cidx;
    }
}

// ---- march: tile-partitioned; blockIdx&63 = tile -> XCD pinning via %8 ----
__global__ __launch_bounds__(256) void march_tiles_kernel(
    const float* __restrict__ compactF, const int* __restrict__ tileCnt,
    const uint32_t* __restrict__ tileList, const uint32_t* __restrict__ quad,
    float* __restrict__ acc)
{
    int tile  = blockIdx.x & 63;
    int chunk = blockIdx.x >> 6;                 // 0..127
    int tx = tile & 3, ty = (tile >> 2) & 3, tz = tile >> 4;
    int group = threadIdx.x >> 3;                // 0..31
    int sub   = threadIdx.x & 7;
    int cnt = tileCnt[tile];
    if (cnt > TILE_CAP) cnt = TILE_CAP;

    float wlx = tile_lo(tx), whx = tile_hi(tx);
    float wly = tile_lo(ty), why = tile_hi(ty);
    float wlz = tile_lo(tz), whz = tile_hi(tz);

    for (int e = chunk * 32 + group; e < cnt; e += 4096) {
        int ridx = tileList[(size_t)tile * TILE_CAP + e];
        const float4* c = (const float4*)(compactF + (size_t)ridx * 8);
        float4 c0 = c[0], c1 = c[1];
        float ox = c0.x, oy = c0.y, oz = c0.z;
        float dx = c0.w, dy = c1.x, dz = c1.y;
        float tmin = c1.z, seg = c1.w;
        float step = seg * (1.0f / (float)N_STEPS);

        float ta = tmin, tb = tmin + seg;
        axis_clip(ox, dx, wlx, whx, ta, tb);
        axis_clip(oy, dy, wly, why, ta, tb);
        axis_clip(oz, dz, wlz, whz, ta, tb);
        if (tb < ta) continue;

        int i_lo = (int)ceilf((ta - tmin) / step - 0.5f - 1e-3f);
        int i_hi = (int)floorf((tb - tmin) / step - 0.5f + 1e-3f);
        i_lo = max(i_lo, 0);
        i_hi = min(i_hi, N_STEPS - 1);

        float sum = 0.0f;
        for (int i = i_lo + sub; i <= i_hi; i += 8) {
            float frac = ((float)i + 0.5f) * (1.0f / (float)N_STEPS);
            float t = fmaf(seg, frac, tmin);
            float px = fmaf(t, dx, ox);
            float py = fmaf(t, dy, oy);
            float pz = fmaf(t, dz, oz);
            float gx = (px + 1.0f) * (0.5f * 255.0f);
            float gy = (py + 1.0f) * (0.5f * 255.0f);
            float gz = (pz + 1.0f) * (0.5f * 255.0f);
            int x0 = (int)fminf(fmaxf(floorf(gx), 0.0f), 254.0f);
            int y0 = (int)fminf(fmaxf(floorf(gy), 0.0f), 254.0f);
            int z0 = (int)fminf(fmaxf(floorf(gz), 0.0f), 254.0f);
            // exact ownership: each sample processed by exactly one tile
            if (((x0 >> 6) != tx) | ((y0 >> 6) != ty) | ((z0 >> 6) != tz)) continue;
            float fx = fminf(fmaxf(gx - (float)x0, 0.0f), 1.0f);
            float fy = fminf(fmaxf(gy - (float)y0, 0.0f), 1.0f);
            float fz = fminf(fmaxf(gz - (float)z0, 0.0f), 1.0f);

            int vidx = (z0 << 16) + (y0 << 8) + x0;
            uint2 v = *(const uint2_a4*)(quad + vidx);
            float c000 = (float)( v.x        & 0xffu);
            float c010 = (float)((v.x >>  8) & 0xffu);
            float c100 = (float)((v.x >> 16) & 0xffu);
            float c110 = (float)( v.x >> 24        );
            float c001 = (float)( v.y        & 0xffu);
            float c011 = (float)((v.y >>  8) & 0xffu);
            float c101 = (float)((v.y >> 16) & 0xffu);
            float c111 = (float)( v.y >> 24        );

            float omfx = 1.0f - fx;
            float c00 = c000 * omfx + c001 * fx;
            float c01 = c010 * omfx + c011 * fx;
            float c10 = c100 * omfx + c101 * fx;
            float c11 = c110 * omfx + c111 * fx;
            float omfy = 1.0f - fy;
            float cc0 = c00 * omfy + c01 * fy;
            float cc1 = c10 * omfy + c11 * fy;
            sum += cc0 * (1.0f - fz) + cc1 * fz;   // scaled by 255
        }

        sum += __shfl_xor(sum, 1);
        sum += __shfl_xor(sum, 2);
        sum += __shfl_xor(sum, 4);
        if (sub == 0 && sum != 0.0f) atomicAdd(&acc[ridx], sum);
    }
}

__global__ __launch_bounds__(256) void finalize_kernel(
    const float* __restrict__ compactF, const int* __restrict__ compactI,
    const int* __restrict__ counter, const float* __restrict__ acc,
    float* __restrict__ out)
{
    int r = blockIdx.x * blockDim.x + threadIdx.x;
    if (r >= *counter) return;
    float seg = compactF[(size_t)r * 8 + 7];
    float dt = seg * (1.0f / (float)N_STEPS);
    float tau = (DENSITY_SCALE / 255.0f) * acc[r] * dt;
    out[compactI[r]] = expf(-tau);
}

// ================= fallback: round-4 path (monolithic march) =================
__global__ __launch_bounds__(256) void setup_kernel(
    const float* __restrict__ rays, float* __restrict__ out,
    float* __restrict__ compactF, int* __restrict__ compactI,
    int* __restrict__ counter, int n_rays)
{
    int ray = blockIdx.x * blockDim.x + threadIdx.x;
    bool valid = false;
    float ox = 0, oy = 0, oz = 0, dx = 0, dy = 0, dz = 0, tmin = 0, seg = 0;
    if (ray < n_rays) {
        const float* r = rays + ray * 6;
        ox = r[0]; oy = r[1]; oz = r[2];
        dx = r[3]; dy = r[4]; dz = r[5];
        float nrm = sqrtf(dx*dx + dy*dy + dz*dz) + REF_EPS;
        float inv_n = 1.0f / nrm;
        dx *= inv_n; dy *= inv_n; dz *= inv_n;
        float ixv = safe_inv(dx), iyv = safe_inv(dy), izv = safe_inv(dz);
        float tax = (-1.0f - ox) * ixv, tbx = (1.0f - ox) * ixv;
        float tay = (-1.0f - oy) * iyv, tby = (1.0f - oy) * iyv;
        float taz = (-1.0f - oz) * izv, tbz = (1.0f - oz) * izv;
        tmin = fmaxf(fmaxf(fminf(tax, tbx), fminf(tay, tby)), fminf(taz, tbz));
        float tmax = fminf(fminf(fmaxf(tax, tbx), fmaxf(tay, tby)), fmaxf(taz, tbz));
        tmin = fmaxf(tmin, 0.0f);
        valid = tmax > tmin;
        seg = valid ? (tmax - tmin) : 0.0f;
    }
    unsigned long long mask = __ballot(valid);
    int lane = threadIdx.x & 63;
    int nbefore = __popcll(mask & ((1ull << lane) - 1ull));
    int total = __popcll(mask);
    int base = 0;
    if (lane == 0 && total) base = atomicAdd(counter, total);
    base = __shfl(base, 0);
    if (valid) {
        int idx = base + nbefore;
        float4* dst = (float4*)(compactF + (size_t)idx * 8);
        dst[0] = make_float4(ox, oy, oz, dx);
        dst[1] = make_float4(dy, dz, tmin, seg);
        compactI[idx] = ray;
    } else if (ray < n_rays) {
        out[ray] = 1.0f;
    }
}

__global__ __launch_bounds__(256) void march_kernel(
    const float* __restrict__ compactF, const int* __restrict__ compactI,
    const int* __restrict__ counter, const uint32_t* __restrict__ quad,
    float* __restrict__ out)
{
    int gid = blockIdx.x * blockDim.x + threadIdx.x;
    int sub = gid & 7;
    int nvalid = *counter;
    int stride = (gridDim.x * blockDim.x) >> 3;
    for (int ray = gid >> 3; ray < nvalid; ray += stride) {
        const float4* c = (const float4*)(compactF + (size_t)ray * 8);
        float4 c0 = c[0], c1 = c[1];
        float ox = c0.x, oy = c0.y, oz = c0.z;
        float dx = c0.w, dy = c1.x, dz = c1.y;
        float tmin = c1.z, seg = c1.w;
        float sum = 0.0f;
        #pragma unroll 4
        for (int i = sub; i < N_STEPS; i += 8) {
            float frac = ((float)i + 0.5f) * (1.0f / (float)N_STEPS);
            float t = fmaf(seg, frac, tmin);
            float px = fmaf(t, dx, ox);
            float py = fmaf(t, dy, oy);
            float pz = fmaf(t, dz, oz);
            float gx = (px + 1.0f) * (0.5f * 255.0f);
            float gy = (py + 1.0f) * (0.5f * 255.0f);
            float gz = (pz + 1.0f) * (0.5f * 255.0f);
            int x0 = (int)fminf(fmaxf(floorf(gx), 0.0f), 254.0f);
            int y0 = (int)fminf(fmaxf(floorf(gy), 0.0f), 254.0f);
            int z0 = (int)fminf(fmaxf(floorf(gz), 0.0f), 254.0f);
            float fx = fminf(fmaxf(gx - (float)x0, 0.0f), 1.0f);
            float fy = fminf(fmaxf(gy - (float)y0, 0.0f), 1.0f);
            float fz = fminf(fmaxf(gz - (float)z0, 0.0f), 1.0f);
            int vidx = (z0 << 16) + (y0 << 8) + x0;
            uint2 v = *(const uint2_a4*)(quad + vidx);
            float c000 = (float)( v.x        & 0xffu);
            float c010 = (float)((v.x >>  8) & 0xffu);
            float c100 = (float)((v.x >> 16) & 0xffu);
            float c110 = (float)( v.x >> 24        );
            float c001 = (float)( v.y        & 0xffu);
            float c011 = (float)((v.y >>  8) & 0xffu);
            float c101 = (float)((v.y >> 16) & 0xffu);
            float c111 = (float)( v.y >> 24        );
            float omfx = 1.0f - fx;
            float c00 = c000 * omfx + c001 * fx;
            float c01 = c010 * omfx + c011 * fx;
            float c10 = c100 * omfx + c101 * fx;
            float c11 = c110 * omfx + c111 * fx;
            float omfy = 1.0f - fy;
            float cc0 = c00 * omfy + c01 * fy;
            float cc1 = c10 * omfy + c11 * fy;
            sum += cc0 * (1.0f - fz) + cc1 * fz;
        }
        sum += __shfl_xor(sum, 1);
        sum += __shfl_xor(sum, 2);
        sum += __shfl_xor(sum, 4);
        if (sub == 0) {
            float dt = seg * (1.0f / (float)N_STEPS);
            float tau = (DENSITY_SCALE / 255.0f) * sum * dt;
            out[compactI[ray]] = expf(-tau);
        }
    }
}

// ================= fallback: round-1 fp32 direct path =================
__global__ __launch_bounds__(256) void transmittance_kernel(
    const float* __restrict__ rays, const float* __restrict__ grid,
    float* __restrict__ out, int n_rays)
{
    int gid = blockIdx.x * blockDim.x + threadIdx.x;
    int ray = gid >> 2;
    int sub = gid & 3;
    if (ray >= n_rays) return;
    const float* r = rays + ray * 6;
    float ox = r[0], oy = r[1], oz = r[2];
    float dx = r[3], dy = r[4], dz = r[5];
    float nrm = sqrtf(dx*dx + dy*dy + dz*dz) + REF_EPS;
    float inv_n = 1.0f / nrm;
    dx *= inv_n; dy *= inv_n; dz *= inv_n;
    float ixv = safe_inv(dx), iyv = safe_inv(dy), izv = safe_inv(dz);
    float tax = (-1.0f - ox) * ixv, tbx = (1.0f - ox) * ixv;
    float tay = (-1.0f - oy) * iyv, tby = (1.0f - oy) * iyv;
    float taz = (-1.0f - oz) * izv, tbz = (1.0f - oz) * izv;
    float tmin = fmaxf(fmaxf(fminf(tax, tbx), fminf(tay, tby)), fminf(taz, tbz));
    float tmax = fminf(fminf(fmaxf(tax, tbx), fmaxf(tay, tby)), fmaxf(taz, tbz));
    tmin = fmaxf(tmin, 0.0f);
    bool valid = tmax > tmin;
    float result = 1.0f;
    float seg = valid ? (tmax - tmin) : 0.0f;
    float sum = 0.0f;
    if (valid) {
        #pragma unroll 4
        for (int i = sub; i < N_STEPS; i += 4) {
            float frac = ((float)i + 0.5f) * (1.0f / (float)N_STEPS);
            float t = fmaf(seg, frac, tmin);
            float px = fmaf(t, dx, ox);
            float py = fmaf(t, dy, oy);
            float pz = fmaf(t, dz, oz);
            float gx = (px + 1.0f) * (0.5f * 255.0f);
            float gy = (py + 1.0f) * (0.5f * 255.0f);
            float gz = (pz + 1.0f) * (0.5f * 255.0f);
            int x0 = (int)fminf(fmaxf(floorf(gx), 0.0f), 254.0f);
            int y0 = (int)fminf(fmaxf(floorf(gy), 0.0f), 254.0f);
            int z0 = (int)fminf(fmaxf(floorf(gz), 0.0f), 254.0f);
            float fx = fminf(fmaxf(gx - (float)x0, 0.0f), 1.0f);
            float fy = fminf(fmaxf(gy - (float)y0, 0.0f), 1.0f);
            float fz = fminf(fmaxf(gz - (float)z0, 0.0f), 1.0f);
            const float* p0 = grid + ((z0 << 16) + (y0 << 8) + x0);
            const float* p1 = p0 + 65536;
            float c000 = p0[0],   c001 = p0[1];
            float c010 = p0[256], c011 = p0[257];
            float c100 = p1[0],   c101 = p1[1];
            float c110 = p1[256], c111 = p1[257];
            float omfx = 1.0f - fx;
            float c00 = c000 * omfx + c001 * fx;
            float c01 = c010 * omfx + c011 * fx;
            float c10 = c100 * omfx + c101 * fx;
            float c11 = c110 * omfx + c111 * fx;
            float omfy = 1.0f - fy;
            float cc0 = c00 * omfy + c01 * fy;
            float cc1 = c10 * omfy + c11 * fy;
            sum += cc0 * (1.0f - fz) + cc1 * fz;
        }
    }
    sum += __shfl_xor(sum, 1);
    sum += __shfl_xor(sum, 2);
    if (valid) {
        float dt = seg * (1.0f / (float)N_STEPS);
        float tau = DENSITY_SCALE * sum * dt;
        result = expf(-tau);
    }
    if (sub == 0) out[ray] = result;
}

extern "C" void kernel_launch(void* const* d_in, const int* in_sizes, int n_in,
                              void* d_out, int out_size, void* d_ws, size_t ws_size,
                              hipStream_t stream) {
    const float* rays = (const float*)d_in[0];   // [65536, 6] fp32
    const float* grid = (const float*)d_in[1];   // [256,256,256] fp32
    float* out = (float*)d_out;
    int n_rays = in_sizes[0] / 6;
    int n_grid = in_sizes[1];                    // 16777216

    const size_t QUAD_BYTES = (size_t)n_grid * 4;            // 64 MB
    const size_t CF_BYTES   = (size_t)n_rays * 8 * 4;        // 2 MB
    const size_t CI_BYTES   = (size_t)n_rays * 4;            // 256 KB
    const size_t TL_BYTES   = (size_t)64 * TILE_CAP * 4;     // 16 MB
    const size_t ACC_BYTES  = (size_t)n_rays * 4;            // 256 KB
    const size_t TC_BYTES   = 64 * 4 + 64;
    const size_t need_tiled = QUAD_BYTES + CF_BYTES + CI_BYTES + TL_BYTES + ACC_BYTES + TC_BYTES;
    const size_t need_mono  = QUAD_BYTES + CF_BYTES + CI_BYTES + 512;

    char* p = (char*)d_ws;
    if (ws_size >= need_tiled) {
        uint32_t* quad     = (uint32_t*)p;                 p += QUAD_BYTES;
        float*    compactF = (float*)p;                    p += CF_BYTES;
        int*      compactI = (int*)p;                      p += CI_BYTES;
        uint32_t* tileList = (uint32_t*)p;                 p += TL_BYTES;
        float*    acc      = (float*)p;                    p += ACC_BYTES;
        int*      tileCnt  = (int*)p;                      p += 64 * 4;
        int*      counter  = (int*)p;

        int rp_threads = n_grid / 4;
        repack_quad_kernel<<<(rp_threads + 255) / 256, 256, 0, stream>>>(
            grid, quad, counter, tileCnt);
        setup_tiles_kernel<<<(n_rays + 255) / 256, 256, 0, stream>>>(
            rays, out, compactF, compactI, counter, tileCnt, tileList, acc, n_rays);
        // 64 tiles x 128 chunks: tile = blockIdx & 63 -> XCD = blockIdx % 8 pins
        // all of tile t's blocks to XCD t%8; oversubscription phases tiles.
        march_tiles_kernel<<<64 * 128, 256, 0, stream>>>(
            compactF, tileCnt, tileList, quad, acc);
        finalize_kernel<<<(n_rays + 255) / 256, 256, 0, stream>>>(
            compactF, compactI, counter, acc, out);
    } else if (ws_size >= need_mono) {
        uint32_t* quad     = (uint32_t*)p;                 p += QUAD_BYTES;
        float*    compactF = (float*)p;                    p += CF_BYTES;
        int*      compactI = (int*)p;                      p += CI_BYTES;
        int*      counter  = (int*)p;                      p += 64;
        int*      tileCntD = (int*)p;                      // dummy, zeroed by repack
        int rp_threads = n_grid / 4;
        repack_quad_kernel<<<(rp_threads + 255) / 256, 256, 0, stream>>>(
            grid, quad, counter, tileCntD);
        setup_kernel<<<(n_rays + 255) / 256, 256, 0, stream>>>(
            rays, out, compactF, compactI, counter, n_rays);
        march_kernel<<<1024, 256, 0, stream>>>(compactF, compactI, counter, quad, out);
    } else {
        int total_threads = n_rays * 4;
        transmittance_kernel<<<(total_threads + 255) / 256, 256, 0, stream>>>(
            rays, grid, out, n_rays);
    }
}